// Round 12
// baseline (53.827 us; speedup 1.0000x reference)
//
#include <hip/hip_runtime.h>
#include <hip/hip_bf16.h>

#define B_ 8
#define L_ 2048
#define D_ 256

typedef __bf16 bf16x8 __attribute__((ext_vector_type(8)));
typedef float f32x4 __attribute__((ext_vector_type(4)));

// round-to-nearest-even f32 -> bf16 (finite inputs)
static __device__ __forceinline__ unsigned short f2bf(float f) {
    unsigned int u = __builtin_bit_cast(unsigned int, f);
    unsigned int lsb = (u >> 16) & 1u;
    u += 0x7fffu + lsb;
    return (unsigned short)(u >> 16);
}

static __device__ __forceinline__ void gload_lds16(const void* g, void* l) {
    __builtin_amdgcn_global_load_lds(
        (const __attribute__((address_space(1))) unsigned int*)g,
        (__attribute__((address_space(3))) unsigned int*)l, 16, 0, 0);
}

// ---------------- prep: A = bf16(c*cqw), Q = bf16(q), s0 = c.cw + bias, s1 = c.qw
__global__ __launch_bounds__(256) void prep_kernel(
    const float* __restrict__ c, const float* __restrict__ q,
    const float* __restrict__ cw, const float* __restrict__ qw,
    const float* __restrict__ cqw, const float* __restrict__ bias,
    unsigned short* __restrict__ Abf, unsigned short* __restrict__ Qbf,
    float* __restrict__ s0, float* __restrict__ s1)
{
    const int wave = threadIdx.x >> 6;
    const int lane = threadIdx.x & 63;
    const int row  = blockIdx.x * 4 + wave;          // 0 .. B*L-1

    const float4 cv  = *(const float4*)(c   + (size_t)row * D_ + lane * 4);
    const float4 qv  = *(const float4*)(q   + (size_t)row * D_ + lane * 4);
    const float4 wc  = *(const float4*)(cw  + lane * 4);
    const float4 wq  = *(const float4*)(qw  + lane * 4);
    const float4 wcq = *(const float4*)(cqw + lane * 4);

    ushort4 av, qb;
    av.x = f2bf(cv.x * wcq.x); av.y = f2bf(cv.y * wcq.y);
    av.z = f2bf(cv.z * wcq.z); av.w = f2bf(cv.w * wcq.w);
    qb.x = f2bf(qv.x); qb.y = f2bf(qv.y);
    qb.z = f2bf(qv.z); qb.w = f2bf(qv.w);
    *(ushort4*)(Abf + (size_t)row * D_ + lane * 4) = av;
    *(ushort4*)(Qbf + (size_t)row * D_ + lane * 4) = qb;

    float p0 = cv.x * wc.x + cv.y * wc.y + cv.z * wc.z + cv.w * wc.w;
    float p1 = cv.x * wq.x + cv.y * wq.y + cv.z * wq.z + cv.w * wq.w;
    #pragma unroll
    for (int off = 32; off > 0; off >>= 1) {
        p0 += __shfl_down(p0, off);
        p1 += __shfl_down(p1, off);
    }
    if (lane == 0) { s0[row] = p0 + bias[0]; s1[row] = p1; }
}

// ---------------- GEMM: out[b,i,j] = s0[i]+s1[j] + sum_k A[i,k]*Q[j,k] -------
// 64x128 tile (M x N), 4 waves each owning a 64x32 column slice. Half-size
// epilogue bursts (32 KB) + 4 blocks/CU (LDS 36KB x4, VGPR<=128) smooth the
// HBM write stream structurally. 3-deep counted-vmcnt pipeline (stage = 3
// loads -> steady vmcnt(6)). Batch->XCD swizzle; small first-round skew.
#define BM 64
#define BN 128
#define BK 32
#define NSTEP (D_ / BK)   // 8

__global__ __launch_bounds__(256, 4) void gemm_kernel(
    const unsigned short* __restrict__ A, const unsigned short* __restrict__ Q,
    const float* __restrict__ s0, const float* __restrict__ s1,
    float* __restrict__ out)
{
    __shared__ __align__(16) unsigned short As[3][BM * BK];   // 3 x 4 KiB
    __shared__ __align__(16) unsigned short Qs[3][BN * BK];   // 3 x 8 KiB

    const int tid  = threadIdx.x;
    const int wave = tid >> 6;
    const int lane = tid & 63;

    // 4096 tiles: batch k -> XCD k; within batch, row-major (32 row x 16 col)
    const int lin = blockIdx.x;                        // 0..4095
    const int nl  = ((lin & 7) << 9) | (lin >> 3);     // bijective
    const int b    = nl >> 9;
    const int brow = ((nl >> 4) & 31) * BM;
    const int bcol = (nl & 15) * BN;

    const unsigned short* Ab = A + ((size_t)b * L_ + brow) * D_;
    const unsigned short* Qb = Q + ((size_t)b * L_ + bcol) * D_;

    f32x4 acc[4][2];
    #pragma unroll
    for (int m = 0; m < 4; ++m)
        #pragma unroll
        for (int n = 0; n < 2; ++n) acc[m][n] = {0.f, 0.f, 0.f, 0.f};

    // --- stage step s into buffer s%3 (1 A + 2 Q gload_lds per thread) ---
    // LDS row = 64B = 4 slots of 16B; slot' = slot ^ ((row>>1)&3)
    auto stage = [&](int s) {
        const int k0 = s * BK;
        unsigned short* ab = &As[s % 3][0];
        unsigned short* qb = &Qs[s % 3][0];
        {   // A: 256 slots, 1/thread
            const int row  = tid >> 2;
            const int sl   = tid & 3;
            const int ksrc = k0 + ((sl ^ ((row >> 1) & 3)) << 3);
            gload_lds16(Ab + (size_t)row * D_ + ksrc, ab + wave * 512);
        }
        #pragma unroll
        for (int i = 0; i < 2; ++i) {   // Q: 512 slots, 2/thread
            const int sidx = i * 256 + tid;
            const int row  = sidx >> 2;
            const int sl   = sidx & 3;
            const int ksrc = k0 + ((sl ^ ((row >> 1) & 3)) << 3);
            gload_lds16(Qb + (size_t)row * D_ + ksrc, qb + (i * 256 + wave * 64) * 8);
        }
    };

    // --- compute step t from buffer t%3 (6 ds_read_b128 + 8 MFMA) ---
    auto compute = [&](int t) {
        const unsigned short* ab = &As[t % 3][0];
        const unsigned short* qb = &Qs[t % 3][0];
        bf16x8 af[4], qf[2];
        #pragma unroll
        for (int m = 0; m < 4; ++m) {
            const int row = m * 16 + (lane & 15);
            const int idx = row * 32 + (((lane >> 4) ^ ((row >> 1) & 3)) << 3);
            af[m] = *(const bf16x8*)(ab + idx);
        }
        #pragma unroll
        for (int n = 0; n < 2; ++n) {
            const int row = wave * 32 + n * 16 + (lane & 15);
            const int idx = row * 32 + (((lane >> 4) ^ ((row >> 1) & 3)) << 3);
            qf[n] = *(const bf16x8*)(qb + idx);
        }
        __builtin_amdgcn_s_setprio(1);
        #pragma unroll
        for (int m = 0; m < 4; ++m)
            #pragma unroll
            for (int n = 0; n < 2; ++n)
                acc[m][n] = __builtin_amdgcn_mfma_f32_16x16x32_bf16(
                    af[m], qf[n], acc[m][n], 0, 0, 0);
        __builtin_amdgcn_s_setprio(0);
    };

    stage(0);
    stage(1);

    // first-round phase skew (cohorts 1..3, ~1.6us apart; 100MHz ticks)
    const int cohort = lin >> 10;            // 0..3
    if (cohort != 0) {
        const unsigned long long dl = (unsigned long long)cohort * 160ULL;
        const unsigned long long t0 = __builtin_amdgcn_s_memrealtime();
        while (__builtin_amdgcn_s_memrealtime() - t0 < dl)
            __builtin_amdgcn_s_sleep(2);
    }

#define STEP(T, VM) do {                                        \
        if ((T) + 2 < NSTEP) stage((T) + 2);                    \
        asm volatile("s_waitcnt vmcnt(" #VM ")" ::: "memory");  \
        __builtin_amdgcn_s_barrier();                           \
        asm volatile("" ::: "memory");                          \
        compute(T);                                             \
        asm volatile("" ::: "memory");                          \
        __builtin_amdgcn_s_barrier();                           \
        asm volatile("" ::: "memory");                          \
    } while (0)

    STEP(0, 6); STEP(1, 6); STEP(2, 6); STEP(3, 6);
    STEP(4, 6); STEP(5, 6); STEP(6, 3); STEP(7, 0);
#undef STEP

    // epilogue: + s0[i] (bias folded) + s1[j]
    const float* s0b = s0 + b * L_ + brow;
    const float* s1b = s1 + b * L_ + bcol + wave * 32;
    float s1v[2];
    #pragma unroll
    for (int n = 0; n < 2; ++n) s1v[n] = s1b[n * 16 + (lane & 15)];
    float* outb = out + ((size_t)b * L_ + brow) * L_ + bcol + wave * 32;
    #pragma unroll
    for (int m = 0; m < 4; ++m) {
        #pragma unroll
        for (int r = 0; r < 4; ++r) {
            const int i = m * 16 + (lane >> 4) * 4 + r;
            const float s0v = s0b[i];
            float* orow = outb + (size_t)i * L_;
            #pragma unroll
            for (int n = 0; n < 2; ++n)
                orow[n * 16 + (lane & 15)] = acc[m][n][r] + s0v + s1v[n];
        }
    }
}

// ---------------- fallback (workspace too small): naive, correct, slow ------
__global__ void naive_kernel(const float* __restrict__ c, const float* __restrict__ q,
                             const float* __restrict__ cw, const float* __restrict__ qw,
                             const float* __restrict__ cqw, const float* __restrict__ bias,
                             float* __restrict__ out)
{
    const size_t total = (size_t)B_ * L_ * L_;
    for (size_t idx = (size_t)blockIdx.x * blockDim.x + threadIdx.x; idx < total;
         idx += (size_t)gridDim.x * blockDim.x) {
        const int b = (int)(idx / ((size_t)L_ * L_));
        const int rem = (int)(idx % ((size_t)L_ * L_));
        const int i = rem / L_, j = rem % L_;
        const float* ci = c + ((size_t)b * L_ + i) * D_;
        const float* cj = c + ((size_t)b * L_ + j) * D_;
        const float* qj = q + ((size_t)b * L_ + j) * D_;
        float acc = bias[0];
        for (int d = 0; d < D_; ++d)
            acc += ci[d] * cw[d] + cj[d] * qw[d] + ci[d] * cqw[d] * qj[d];
        out[idx] = acc;
    }
}

extern "C" void kernel_launch(void* const* d_in, const int* in_sizes, int n_in,
                              void* d_out, int out_size, void* d_ws, size_t ws_size,
                              hipStream_t stream) {
    const float* c    = (const float*)d_in[0];
    const float* q    = (const float*)d_in[1];
    const float* cw   = (const float*)d_in[2];
    const float* qw   = (const float*)d_in[3];
    const float* cqw  = (const float*)d_in[4];
    const float* bias = (const float*)d_in[5];
    float* out = (float*)d_out;

    const size_t bytesA = (size_t)B_ * L_ * D_ * 2;            // 8 MiB
    const size_t need   = 2 * bytesA + 2 * (size_t)B_ * L_ * 4; // ~16.1 MiB

    if (ws_size >= need) {
        unsigned short* Abf = (unsigned short*)d_ws;
        unsigned short* Qbf = (unsigned short*)((char*)d_ws + bytesA);
        float* s0 = (float*)((char*)d_ws + 2 * bytesA);
        float* s1 = s0 + (size_t)B_ * L_;
        prep_kernel<<<B_ * L_ / 4, 256, 0, stream>>>(c, q, cw, qw, cqw, bias,
                                                     Abf, Qbf, s0, s1);
        gemm_kernel<<<dim3(4096), 256, 0, stream>>>(Abf, Qbf, s0, s1, out);
    } else {
        naive_kernel<<<2048, 256, 0, stream>>>(c, q, cw, qw, cqw, bias, out);
    }
}

// Round 13
// 44.551 us; speedup vs baseline: 1.2082x; 1.2082x over previous
//
#include <hip/hip_runtime.h>
#include <hip/hip_bf16.h>

#define B_ 8
#define L_ 2048
#define D_ 256

typedef __bf16 bf16x8 __attribute__((ext_vector_type(8)));
typedef float f32x4 __attribute__((ext_vector_type(4)));

// round-to-nearest-even f32 -> bf16 (finite inputs)
static __device__ __forceinline__ unsigned short f2bf(float f) {
    unsigned int u = __builtin_bit_cast(unsigned int, f);
    unsigned int lsb = (u >> 16) & 1u;
    u += 0x7fffu + lsb;
    return (unsigned short)(u >> 16);
}

static __device__ __forceinline__ void gload_lds16(const void* g, void* l) {
    __builtin_amdgcn_global_load_lds(
        (const __attribute__((address_space(1))) unsigned int*)g,
        (__attribute__((address_space(3))) unsigned int*)l, 16, 0, 0);
}

// ---------------- prep: A = bf16(c*cqw), Q = bf16(q), s0 = c.cw + bias, s1 = c.qw
__global__ __launch_bounds__(256) void prep_kernel(
    const float* __restrict__ c, const float* __restrict__ q,
    const float* __restrict__ cw, const float* __restrict__ qw,
    const float* __restrict__ cqw, const float* __restrict__ bias,
    unsigned short* __restrict__ Abf, unsigned short* __restrict__ Qbf,
    float* __restrict__ s0, float* __restrict__ s1)
{
    const int wave = threadIdx.x >> 6;
    const int lane = threadIdx.x & 63;
    const int row  = blockIdx.x * 4 + wave;          // 0 .. B*L-1

    const float4 cv  = *(const float4*)(c   + (size_t)row * D_ + lane * 4);
    const float4 qv  = *(const float4*)(q   + (size_t)row * D_ + lane * 4);
    const float4 wc  = *(const float4*)(cw  + lane * 4);
    const float4 wq  = *(const float4*)(qw  + lane * 4);
    const float4 wcq = *(const float4*)(cqw + lane * 4);

    ushort4 av, qb;
    av.x = f2bf(cv.x * wcq.x); av.y = f2bf(cv.y * wcq.y);
    av.z = f2bf(cv.z * wcq.z); av.w = f2bf(cv.w * wcq.w);
    qb.x = f2bf(qv.x); qb.y = f2bf(qv.y);
    qb.z = f2bf(qv.z); qb.w = f2bf(qv.w);
    *(ushort4*)(Abf + (size_t)row * D_ + lane * 4) = av;
    *(ushort4*)(Qbf + (size_t)row * D_ + lane * 4) = qb;

    float p0 = cv.x * wc.x + cv.y * wc.y + cv.z * wc.z + cv.w * wc.w;
    float p1 = cv.x * wq.x + cv.y * wq.y + cv.z * wq.z + cv.w * wq.w;
    #pragma unroll
    for (int off = 32; off > 0; off >>= 1) {
        p0 += __shfl_down(p0, off);
        p1 += __shfl_down(p1, off);
    }
    if (lane == 0) { s0[row] = p0 + bias[0]; s1[row] = p1; }
}

// ---------------- GEMM: out[b,i,j] = s0[i]+s1[j] + sum_k A[i,k]*Q[j,k] -------
// 128x128 tile, BK=32, 2-deep counted-vmcnt pipeline (LDS 32 KB) so 4 blocks
// fit per CU (__launch_bounds__(256,4), VGPR<=128): 4 co-resident store
// bursts interleave per CU. Stage(t+1) is issued before compute(t) and
// vmcnt(4) waits only for stage(t) -- never a drain. Phase skew 1.6us apart
// for the 4 first-round cohorts (= store-burst drain time, measured R8-R10).
#define BM 128
#define BN 128
#define BK 32
#define NSTEP (D_ / BK)   // 8

__global__ __launch_bounds__(256, 4) void gemm_kernel(
    const unsigned short* __restrict__ A, const unsigned short* __restrict__ Q,
    const float* __restrict__ s0, const float* __restrict__ s1,
    float* __restrict__ out)
{
    __shared__ __align__(16) unsigned short As[2][BM * BK];   // 2 x 8 KiB
    __shared__ __align__(16) unsigned short Qs[2][BM * BK];   // 2 x 8 KiB

    const int tid  = threadIdx.x;
    const int wave = tid >> 6;
    const int lane = tid & 63;

    // XCD-chunked bijective swizzle: batch k -> XCD k
    const int lin = blockIdx.x + (blockIdx.y << 4) + (blockIdx.z << 8); // 0..2047
    const int nl  = ((lin & 7) << 8) | (lin >> 3);
    const int b   = nl >> 8;
    const int brow = ((nl >> 4) & 15) * BM;
    const int bcol = (nl & 15) * BN;

    const unsigned short* Ab = A + ((size_t)b * L_ + brow) * D_;
    const unsigned short* Qb = Q + ((size_t)b * L_ + bcol) * D_;

    const int wr = wave >> 1;   // 0..1
    const int wc = wave & 1;    // 0..1

    const f32x4 zero = {0.f, 0.f, 0.f, 0.f};
    f32x4 acc[4][4];
    #pragma unroll
    for (int m = 0; m < 4; ++m)
        #pragma unroll
        for (int n = 0; n < 4; ++n) acc[m][n] = zero;

    // --- stage step s into buffer s%2 (4 gload_lds/thread) ---
    auto stage = [&](int s) {
        const int k0 = s * BK;
        unsigned short* ab = &As[s & 1][0];
        unsigned short* qb = &Qs[s & 1][0];
        #pragma unroll
        for (int i = 0; i < 2; ++i) {
            const int sidx = i * 256 + wave * 64 + lane;   // slot index 0..511
            const int row  = sidx >> 2;                    // 0..127
            const int sl   = sidx & 3;
            const int ksrc = k0 + ((sl ^ ((row >> 1) & 3)) << 3);
            const int wbase = (i * 256 + wave * 64) * 8;   // ushort idx of wave base
            gload_lds16(Ab + (size_t)row * D_ + ksrc, ab + wbase);
            gload_lds16(Qb + (size_t)row * D_ + ksrc, qb + wbase);
        }
    };

    // --- compute step t from buffer t%2 (8 ds_read_b128 + 16 MFMA) ---
    auto compute = [&](int t) {
        const unsigned short* ab = &As[t & 1][0];
        const unsigned short* qb = &Qs[t & 1][0];
        bf16x8 af[4], qf[4];
        #pragma unroll
        for (int m = 0; m < 4; ++m) {
            const int row = wr * 64 + m * 16 + (lane & 15);
            const int idx = row * 32 + (((lane >> 4) ^ ((row >> 1) & 3)) << 3);
            af[m] = *(const bf16x8*)(ab + idx);
        }
        #pragma unroll
        for (int n = 0; n < 4; ++n) {
            const int row = wc * 64 + n * 16 + (lane & 15);
            const int idx = row * 32 + (((lane >> 4) ^ ((row >> 1) & 3)) << 3);
            qf[n] = *(const bf16x8*)(qb + idx);
        }
        __builtin_amdgcn_s_setprio(1);
        #pragma unroll
        for (int m = 0; m < 4; ++m)
            #pragma unroll
            for (int n = 0; n < 4; ++n)
                acc[m][n] = __builtin_amdgcn_mfma_f32_16x16x32_bf16(
                    af[m], qf[n], acc[m][n], 0, 0, 0);
        __builtin_amdgcn_s_setprio(0);
    };

    stage(0);

    // --- phase skew: first-round cohorts 1..3 wait 1.6/3.2/4.8us (100MHz) ---
    const int cohort = lin >> 8;             // 0..7
    if (cohort >= 1 && cohort <= 3) {
        const unsigned long long dl = (unsigned long long)cohort * 160ULL;
        const unsigned long long t0 = __builtin_amdgcn_s_memrealtime();
        while (__builtin_amdgcn_s_memrealtime() - t0 < dl)
            __builtin_amdgcn_s_sleep(2);
    }

#define STEP(T, VM) do {                                        \
        if ((T) + 1 < NSTEP) stage((T) + 1);                    \
        asm volatile("s_waitcnt vmcnt(" #VM ")" ::: "memory");  \
        __builtin_amdgcn_s_barrier();                           \
        asm volatile("" ::: "memory");                          \
        compute(T);                                             \
        asm volatile("" ::: "memory");                          \
        __builtin_amdgcn_s_barrier();                           \
        asm volatile("" ::: "memory");                          \
    } while (0)

    STEP(0, 4); STEP(1, 4); STEP(2, 4); STEP(3, 4);
    STEP(4, 4); STEP(5, 4); STEP(6, 4); STEP(7, 0);
#undef STEP

    // epilogue: + s0[i] (bias folded) + s1[j]
    const float* s0b = s0 + b * L_ + brow;
    const float* s1b = s1 + b * L_ + bcol;
    float s1v[4];
    #pragma unroll
    for (int n = 0; n < 4; ++n) s1v[n] = s1b[wc * 64 + n * 16 + (lane & 15)];
    float* outb = out + ((size_t)b * L_ + brow) * L_ + bcol;
    #pragma unroll
    for (int m = 0; m < 4; ++m) {
        #pragma unroll
        for (int r = 0; r < 4; ++r) {
            const int i = wr * 64 + m * 16 + (lane >> 4) * 4 + r;
            const float s0v = s0b[i];
            float* orow = outb + (size_t)i * L_;
            #pragma unroll
            for (int n = 0; n < 4; ++n)
                orow[wc * 64 + n * 16 + (lane & 15)] = acc[m][n][r] + s0v + s1v[n];
        }
    }
}

// ---------------- fallback (workspace too small): naive, correct, slow ------
__global__ void naive_kernel(const float* __restrict__ c, const float* __restrict__ q,
                             const float* __restrict__ cw, const float* __restrict__ qw,
                             const float* __restrict__ cqw, const float* __restrict__ bias,
                             float* __restrict__ out)
{
    const size_t total = (size_t)B_ * L_ * L_;
    for (size_t idx = (size_t)blockIdx.x * blockDim.x + threadIdx.x; idx < total;
         idx += (size_t)gridDim.x * blockDim.x) {
        const int b = (int)(idx / ((size_t)L_ * L_));
        const int rem = (int)(idx % ((size_t)L_ * L_));
        const int i = rem / L_, j = rem % L_;
        const float* ci = c + ((size_t)b * L_ + i) * D_;
        const float* cj = c + ((size_t)b * L_ + j) * D_;
        const float* qj = q + ((size_t)b * L_ + j) * D_;
        float acc = bias[0];
        for (int d = 0; d < D_; ++d)
            acc += ci[d] * cw[d] + cj[d] * qw[d] + ci[d] * cqw[d] * qj[d];
        out[idx] = acc;
    }
}

extern "C" void kernel_launch(void* const* d_in, const int* in_sizes, int n_in,
                              void* d_out, int out_size, void* d_ws, size_t ws_size,
                              hipStream_t stream) {
    const float* c    = (const float*)d_in[0];
    const float* q    = (const float*)d_in[1];
    const float* cw   = (const float*)d_in[2];
    const float* qw   = (const float*)d_in[3];
    const float* cqw  = (const float*)d_in[4];
    const float* bias = (const float*)d_in[5];
    float* out = (float*)d_out;

    const size_t bytesA = (size_t)B_ * L_ * D_ * 2;            // 8 MiB
    const size_t need   = 2 * bytesA + 2 * (size_t)B_ * L_ * 4; // ~16.1 MiB

    if (ws_size >= need) {
        unsigned short* Abf = (unsigned short*)d_ws;
        unsigned short* Qbf = (unsigned short*)((char*)d_ws + bytesA);
        float* s0 = (float*)((char*)d_ws + 2 * bytesA);
        float* s1 = s0 + (size_t)B_ * L_;
        prep_kernel<<<B_ * L_ / 4, 256, 0, stream>>>(c, q, cw, qw, cqw, bias,
                                                     Abf, Qbf, s0, s1);
        dim3 grid(L_ / BN, L_ / BM, B_);
        gemm_kernel<<<grid, 256, 0, stream>>>(Abf, Qbf, s0, s1, out);
    } else {
        naive_kernel<<<2048, 256, 0, stream>>>(c, q, cw, qw, cqw, bias, out);
    }
}